// Round 5
// baseline (118.885 us; speedup 1.0000x reference)
//
#include <hip/hip_runtime.h>

// B=4, C=64, H=64, W=64. Tokens N = C*H = 4096, feature dim D = W = 64.
// q = conv1x1(v1,wq,bq); k,v = conv1x1(v2,...); scores = q@k^T (no scale);
// softmax; out = attn@v. Output fp32, flat (B,C,H,W) == (B,N,D).
//
// R5: attn was latency-bound (all pipes <30%): barrier convoy around LDS
// staging. K/V slices are L2-resident -> load MFMA fragments DIRECTLY from
// global (no K/V LDS, no __syncthreads at all). Pt stays (wave-private).
// S=16 splits, f16 Opart partials, conv split 6-way.

#define Bn 4
#define Cc 64
#define HW 4096
#define Nn 4096
#define Dd 64
#define TS (Bn * Nn * Dd)   // elems per (B,N,D) tensor = 1048576

typedef _Float16 f16;
typedef _Float16 f16x8 __attribute__((ext_vector_type(8)));
typedef _Float16 f16x4 __attribute__((ext_vector_type(4)));
typedef float f32x4 __attribute__((ext_vector_type(4)));

__device__ __forceinline__ int swz(int row, int col) {
    return row * 64 + (col ^ ((row & 7) << 3));
}

// ---------------------------------------------------------------------------
// Kernel 1: 1x1 conv. blockIdx.z in 0..5: tensor = z>>1, channel-half = z&1.
// 8 output channels per thread, 64 positions per block. SGPR weight reads.
__global__ __launch_bounds__(256) void qkv_conv(
    const float* __restrict__ v1, const float* __restrict__ v2,
    const float* __restrict__ wq, const float* __restrict__ bq,
    const float* __restrict__ wk, const float* __restrict__ bk,
    const float* __restrict__ wv, const float* __restrict__ bv,
    f16* __restrict__ Qh, f16* __restrict__ Ql,
    f16* __restrict__ Kh, f16* __restrict__ Vh)
{
    const int t    = threadIdx.x;
    const int lane = t & 63;
    const int og   = __builtin_amdgcn_readfirstlane(t >> 6);  // 0..3, uniform
    const int b    = blockIdx.y;
    const int p    = blockIdx.x * 64 + lane;
    const int z    = blockIdx.z;        // 0..5
    const int zt   = z >> 1;            // 0=Q, 1=K, 2=V
    const int ch0  = (z & 1) * 32 + og * 8;

    const float* w    = (zt == 0) ? wq : (zt == 1) ? wk : wv;
    const float* bias = (zt == 0) ? bq : (zt == 1) ? bk : bv;
    const float* x    = ((zt == 0) ? v1 : v2) + (size_t)b * (Cc * HW) + p;

    float acc[8];
    #pragma unroll
    for (int j = 0; j < 8; ++j) acc[j] = bias[ch0 + j];
    #pragma unroll 16
    for (int c = 0; c < 64; ++c) {
        float xc = x[c * HW];
        #pragma unroll
        for (int j = 0; j < 8; ++j)
            acc[j] = fmaf(w[(ch0 + j) * 64 + c], xc, acc[j]);
    }

    if (zt == 0) {
        #pragma unroll
        for (int j = 0; j < 8; ++j) {
            size_t idx = (size_t)b * (Nn * Dd) + (size_t)(ch0 + j) * 4096 + p;
            f16 hi = (f16)acc[j];
            Qh[idx] = hi;
            Ql[idx] = (f16)(acc[j] - (float)hi);
        }
    } else {
        f16* dst = (zt == 1) ? Kh : Vh;
        #pragma unroll
        for (int j = 0; j < 8; ++j) {
            size_t idx = (size_t)b * (Nn * Dd) + (size_t)(ch0 + j) * 4096 + p;
            dst[idx] = (f16)acc[j];
        }
    }
}

// ---------------------------------------------------------------------------
// Kernel 2: transpose V (B,N,D) -> Vt (B,D,N).
__global__ __launch_bounds__(256) void vtrans(const f16* __restrict__ Vh,
                                              f16* __restrict__ Vt)
{
    __shared__ f16 tile[64][72];
    const int t  = threadIdx.x;
    const int n0 = blockIdx.x * 64;
    const int b  = blockIdx.y;
    for (int i = t; i < 4096; i += 256) {
        int r = i >> 6, c = i & 63;
        tile[r][c] = Vh[(size_t)b * (Nn * Dd) + (size_t)(n0 + r) * 64 + c];
    }
    __syncthreads();
    for (int i = t; i < 4096; i += 256) {
        int w = i >> 6, n = i & 63;
        Vt[(size_t)b * (Dd * Nn) + (size_t)w * Nn + n0 + n] = tile[n][w];
    }
}

// ---------------------------------------------------------------------------
// Kernel 3: flash attention, split-K, NO barriers / NO K,V LDS staging.
// grid (32 q-blocks of 128 rows, S splits, 4 batches) x 256 threads (4 waves,
// 32 q-rows each, fully independent). K/V fragments load straight from L2.
// S^T = mfma(A=Kh, B=Q^T): lane holds S[key=fm*16+g*4+r][qrow c of frag qf].
__global__ __launch_bounds__(256, 4) void attn(
    const f16* __restrict__ Qhg, const f16* __restrict__ Qlg,
    const f16* __restrict__ Khg, const f16* __restrict__ Vtg,
    float* __restrict__ out, f16* __restrict__ Opart, float2* __restrict__ ml)
{
    __shared__ __align__(16) f16 Pt[8192];   // [128 qrows][64 keys] swizzled

    const int t    = threadIdx.x;
    const int lane = t & 63, wvi = t >> 6;
    const int g = lane >> 4, c = lane & 15;
    const int b  = blockIdx.z;
    const int sp = blockIdx.y;
    const int S  = gridDim.y;
    const int n0 = blockIdx.x * 128;
    const int keysPerSplit = Nn / S;
    const int nTiles = keysPerSplit / 64;
    const int kbase = sp * keysPerSplit;

    // Hoist Q B-fragments (hi/lo) for both 16-row sub-frags.
    f16x8 qbh[2][2], qbl[2][2];
    #pragma unroll
    for (int qf = 0; qf < 2; ++qf) {
        const int qrow = n0 + wvi * 32 + qf * 16 + c;
        const f16* qhp = Qhg + ((size_t)b * Nn + qrow) * 64;
        const f16* qlp = Qlg + ((size_t)b * Nn + qrow) * 64;
        #pragma unroll
        for (int ks = 0; ks < 2; ++ks) {
            qbh[qf][ks] = *(const f16x8*)(qhp + ks * 32 + g * 8);
            qbl[qf][ks] = *(const f16x8*)(qlp + ks * 32 + g * 8);
        }
    }

    float m_run[2] = {-1e30f, -1e30f}, l_run[2] = {0.f, 0.f};
    f32x4 of[2][4];
    #pragma unroll
    for (int qf = 0; qf < 2; ++qf)
        #pragma unroll
        for (int nf = 0; nf < 4; ++nf)
            #pragma unroll
            for (int r = 0; r < 4; ++r) of[qf][nf][r] = 0.f;

    const f16* Kb = Khg + (size_t)b * Nn * 64;
    const f16* Vb = Vtg + (size_t)b * Dd * 64 * 64;   // b*Dd*Nn

    for (int kt = 0; kt < nTiles; ++kt) {
        const int k0 = kbase + kt * 64;

        // ---- QK^T: K A-frags direct from global (L2), 2-pass hi/lo ----
        f32x4 accS[2][4];
        #pragma unroll
        for (int qf = 0; qf < 2; ++qf)
            #pragma unroll
            for (int fm = 0; fm < 4; ++fm)
                #pragma unroll
                for (int r = 0; r < 4; ++r) accS[qf][fm][r] = 0.f;
        #pragma unroll
        for (int fm = 0; fm < 4; ++fm) {
            const f16* kp = Kb + (size_t)(k0 + fm * 16 + c) * 64 + g * 8;
            f16x8 kh0 = *(const f16x8*)(kp);
            f16x8 kh1 = *(const f16x8*)(kp + 32);
            #pragma unroll
            for (int qf = 0; qf < 2; ++qf) {
                accS[qf][fm] = __builtin_amdgcn_mfma_f32_16x16x32_f16(kh0, qbl[qf][0], accS[qf][fm], 0, 0, 0);
                accS[qf][fm] = __builtin_amdgcn_mfma_f32_16x16x32_f16(kh0, qbh[qf][0], accS[qf][fm], 0, 0, 0);
                accS[qf][fm] = __builtin_amdgcn_mfma_f32_16x16x32_f16(kh1, qbl[qf][1], accS[qf][fm], 0, 0, 0);
                accS[qf][fm] = __builtin_amdgcn_mfma_f32_16x16x32_f16(kh1, qbh[qf][1], accS[qf][fm], 0, 0, 0);
            }
        }

        // ---- online softmax per q-frag (lane's scores belong to q-row c) ----
        float corr[2];
        #pragma unroll
        for (int qf = 0; qf < 2; ++qf) {
            float tmax = -1e30f;
            #pragma unroll
            for (int fm = 0; fm < 4; ++fm)
                #pragma unroll
                for (int r = 0; r < 4; ++r) tmax = fmaxf(tmax, accS[qf][fm][r]);
            tmax = fmaxf(tmax, __shfl_xor(tmax, 16));
            tmax = fmaxf(tmax, __shfl_xor(tmax, 32));
            const float mnew = fmaxf(m_run[qf], tmax);
            corr[qf] = __expf(m_run[qf] - mnew);
            float tsum = 0.f;
            #pragma unroll
            for (int fm = 0; fm < 4; ++fm)
                #pragma unroll
                for (int r = 0; r < 4; ++r) {
                    float pp = __expf(accS[qf][fm][r] - mnew);
                    accS[qf][fm][r] = pp;
                    tsum += pp;
                }
            tsum += __shfl_xor(tsum, 16);
            tsum += __shfl_xor(tsum, 32);
            l_run[qf] = l_run[qf] * corr[qf] + tsum;
            m_run[qf] = mnew;
        }

        // ---- rescale O, stash P to LDS (wave-private rows, no barrier) ----
        #pragma unroll
        for (int qf = 0; qf < 2; ++qf) {
            #pragma unroll
            for (int r = 0; r < 4; ++r) {
                float cr = __shfl(corr[qf], g * 4 + r);
                #pragma unroll
                for (int nf = 0; nf < 4; ++nf) of[qf][nf][r] *= cr;
            }
            const int prow = wvi * 32 + qf * 16 + c;
            #pragma unroll
            for (int fm = 0; fm < 4; ++fm) {
                f16x4 pk;
                #pragma unroll
                for (int r = 0; r < 4; ++r) pk[r] = (f16)accS[qf][fm][r];
                *(f16x4*)(Pt + swz(prow, fm * 16 + g * 4)) = pk;
            }
        }

        // ---- PV: V B-frags direct from global; one V-read feeds both qf ----
        #pragma unroll
        for (int ks = 0; ks < 2; ++ks) {
            f16x8 pa0 = *(const f16x8*)(Pt + swz(wvi * 32 + c,      ks * 32 + g * 8));
            f16x8 pa1 = *(const f16x8*)(Pt + swz(wvi * 32 + 16 + c, ks * 32 + g * 8));
            #pragma unroll
            for (int nf = 0; nf < 4; ++nf) {
                f16x8 vb = *(const f16x8*)(Vb + (size_t)(nf * 16 + c) * Nn + k0 + ks * 32 + g * 8);
                of[0][nf] = __builtin_amdgcn_mfma_f32_16x16x32_f16(pa0, vb, of[0][nf], 0, 0, 0);
                of[1][nf] = __builtin_amdgcn_mfma_f32_16x16x32_f16(pa1, vb, of[1][nf], 0, 0, 0);
            }
        }
    }

    if (S == 1) {
        #pragma unroll
        for (int qf = 0; qf < 2; ++qf) {
            const float linv = 1.0f / l_run[qf];
            #pragma unroll
            for (int r = 0; r < 4; ++r) {
                float li = __shfl(linv, g * 4 + r);
                int n = n0 + wvi * 32 + qf * 16 + g * 4 + r;
                #pragma unroll
                for (int nf = 0; nf < 4; ++nf)
                    out[((size_t)b * Nn + n) * 64 + nf * 16 + c] = of[qf][nf][r] * li;
            }
        }
    } else {
        #pragma unroll
        for (int qf = 0; qf < 2; ++qf) {
            #pragma unroll
            for (int r = 0; r < 4; ++r) {
                int n = n0 + wvi * 32 + qf * 16 + g * 4 + r;
                size_t robase = (((size_t)sp * Bn + b) * Nn + n) * 64;
                #pragma unroll
                for (int nf = 0; nf < 4; ++nf)
                    Opart[robase + nf * 16 + c] = (f16)of[qf][nf][r];
            }
            if (lane < 16) {
                int n = n0 + wvi * 32 + qf * 16 + c;
                ml[((size_t)sp * Bn + b) * Nn + n] = make_float2(m_run[qf], l_run[qf]);
            }
        }
    }
}

// ---------------------------------------------------------------------------
// Kernel 4: combine split partials. 8 outputs per thread (f16x8 reads).
__global__ __launch_bounds__(256) void combine(
    const f16* __restrict__ Opart, const float2* __restrict__ ml,
    float* __restrict__ out, int S)
{
    const int idx8 = blockIdx.x * 256 + threadIdx.x;  // b*(N*8) + n*8 + w8
    const int w8 = idx8 & 7;
    const int n  = (idx8 >> 3) & (Nn - 1);
    const int b  = idx8 >> 15;
    float M = -1e30f;
    for (int s = 0; s < S; ++s)
        M = fmaxf(M, ml[((size_t)s * Bn + b) * Nn + n].x);
    float num[8];
    #pragma unroll
    for (int j = 0; j < 8; ++j) num[j] = 0.f;
    float den = 0.f;
    for (int s = 0; s < S; ++s) {
        float2 m2 = ml[((size_t)s * Bn + b) * Nn + n];
        float a = __expf(m2.x - M);
        f16x8 o8 = *(const f16x8*)(Opart + ((((size_t)s * Bn + b) * Nn + n) << 6) + w8 * 8);
        #pragma unroll
        for (int j = 0; j < 8; ++j) num[j] += a * (float)o8[j];
        den += a * m2.y;
    }
    const float di = 1.0f / den;
    float* op = out + (((size_t)b * Nn + n) << 6) + w8 * 8;
    float4 lo = make_float4(num[0] * di, num[1] * di, num[2] * di, num[3] * di);
    float4 hi = make_float4(num[4] * di, num[5] * di, num[6] * di, num[7] * di);
    *(float4*)op = lo;
    *(float4*)(op + 4) = hi;
}

// ---------------------------------------------------------------------------
extern "C" void kernel_launch(void* const* d_in, const int* in_sizes, int n_in,
                              void* d_out, int out_size, void* d_ws, size_t ws_size,
                              hipStream_t stream)
{
    const float* v1 = (const float*)d_in[0];
    const float* v2 = (const float*)d_in[1];
    const float* wq = (const float*)d_in[2];
    const float* bq = (const float*)d_in[3];
    const float* wk = (const float*)d_in[4];
    const float* bk = (const float*)d_in[5];
    const float* wv = (const float*)d_in[6];
    const float* bv = (const float*)d_in[7];
    float* out = (float*)d_out;

    char* ws = (char*)d_ws;
    const size_t T = (size_t)TS * sizeof(f16);  // 2 MB per f16 tensor
    f16* Qh = (f16*)(ws + 0 * T);
    f16* Ql = (f16*)(ws + 1 * T);
    f16* Kh = (f16*)(ws + 2 * T);
    f16* Vh = (f16*)(ws + 3 * T);
    f16* Vt = (f16*)(ws + 4 * T);
    const size_t base = 5 * T;                       // 10 MB
    const size_t opartBytes = (size_t)TS * 2;        // 2 MB per split (f16)
    const size_t mlBytes    = (size_t)Bn * Nn * 8;   // 128 KB per split

    int S = 1;
    if      (ws_size >= base + 16 * (opartBytes + mlBytes)) S = 16;
    else if (ws_size >= base +  8 * (opartBytes + mlBytes)) S = 8;
    else if (ws_size >= base +  4 * (opartBytes + mlBytes)) S = 4;
    else if (ws_size >= base +  2 * (opartBytes + mlBytes)) S = 2;

    f16*    Opart = (f16*)(ws + base);
    float2* mlp   = (float2*)(ws + base + (size_t)S * opartBytes);

    qkv_conv<<<dim3(64, 4, 6), 256, 0, stream>>>(v1, v2, wq, bq, wk, bk, wv, bv,
                                                 Qh, Ql, Kh, Vh);
    vtrans<<<dim3(64, 4), 256, 0, stream>>>(Vh, Vt);
    attn<<<dim3(32, S, 4), 256, 0, stream>>>(Qh, Ql, Kh, Vt, out, Opart, mlp);
    if (S > 1) {
        combine<<<(Bn * Nn * Dd / 8) / 256, 256, 0, stream>>>(Opart, mlp, out, S);
    }
}

// Round 6
// 82.398 us; speedup vs baseline: 1.4428x; 1.4428x over previous
//
#include <hip/hip_runtime.h>

// B=4, C=64, H=64, W=64. Tokens N = C*H = 4096, feature dim D = W = 64.
// q = conv1x1(v1,wq,bq); k,v = conv1x1(v2,...); scores = q@k^T (no scale);
// softmax; out = attn@v. Output fp32, flat (B,C,H,W) == (B,N,D).
//
// R6: revert R5's direct-global K/V (4x traffic, L2-latency-bound). R4 base +
//  (1) double-buffered K/V LDS -> single barrier per tile,
//  (2) defer-max (THR=8 log2) skips O-rescale most tiles; normalized f16 partials,
//  (3) log2e folded into Q at conv -> exp2f softmax, tree reductions,
//  (4) S=16 splits.

#define Bn 4
#define Cc 64
#define HW 4096
#define Nn 4096
#define Dd 64
#define TS (Bn * Nn * Dd)   // elems per (B,N,D) tensor = 1048576
#define LOG2E 1.44269504088896340736f

typedef _Float16 f16;
typedef _Float16 f16x8 __attribute__((ext_vector_type(8)));
typedef _Float16 f16x4 __attribute__((ext_vector_type(4)));
typedef float f32x4 __attribute__((ext_vector_type(4)));

__device__ __forceinline__ int swz(int row, int col) {
    return row * 64 + (col ^ ((row & 7) << 3));
}

// ---------------------------------------------------------------------------
// Kernel 1: 1x1 conv. blockIdx.z in 0..5: tensor = z>>1, channel-half = z&1.
// Q path is pre-scaled by log2(e) so attention can use native exp2.
__global__ __launch_bounds__(256) void qkv_conv(
    const float* __restrict__ v1, const float* __restrict__ v2,
    const float* __restrict__ wq, const float* __restrict__ bq,
    const float* __restrict__ wk, const float* __restrict__ bk,
    const float* __restrict__ wv, const float* __restrict__ bv,
    f16* __restrict__ Qh, f16* __restrict__ Ql,
    f16* __restrict__ Kh, f16* __restrict__ Vh)
{
    const int t    = threadIdx.x;
    const int lane = t & 63;
    const int og   = __builtin_amdgcn_readfirstlane(t >> 6);  // 0..3, uniform
    const int b    = blockIdx.y;
    const int p    = blockIdx.x * 64 + lane;
    const int z    = blockIdx.z;        // 0..5
    const int zt   = z >> 1;            // 0=Q, 1=K, 2=V
    const int ch0  = (z & 1) * 32 + og * 8;

    const float* w    = (zt == 0) ? wq : (zt == 1) ? wk : wv;
    const float* bias = (zt == 0) ? bq : (zt == 1) ? bk : bv;
    const float* x    = ((zt == 0) ? v1 : v2) + (size_t)b * (Cc * HW) + p;

    float acc[8];
    #pragma unroll
    for (int j = 0; j < 8; ++j) acc[j] = bias[ch0 + j];
    #pragma unroll 16
    for (int c = 0; c < 64; ++c) {
        float xc = x[c * HW];
        #pragma unroll
        for (int j = 0; j < 8; ++j)
            acc[j] = fmaf(w[(ch0 + j) * 64 + c], xc, acc[j]);
    }

    if (zt == 0) {
        #pragma unroll
        for (int j = 0; j < 8; ++j) {
            size_t idx = (size_t)b * (Nn * Dd) + (size_t)(ch0 + j) * 4096 + p;
            float qs = acc[j] * LOG2E;           // fold log2(e) into Q
            f16 hi = (f16)qs;
            Qh[idx] = hi;
            Ql[idx] = (f16)(qs - (float)hi);
        }
    } else {
        f16* dst = (zt == 1) ? Kh : Vh;
        #pragma unroll
        for (int j = 0; j < 8; ++j) {
            size_t idx = (size_t)b * (Nn * Dd) + (size_t)(ch0 + j) * 4096 + p;
            dst[idx] = (f16)acc[j];
        }
    }
}

// ---------------------------------------------------------------------------
// Kernel 2: transpose V (B,N,D) -> Vt (B,D,N).
__global__ __launch_bounds__(256) void vtrans(const f16* __restrict__ Vh,
                                              f16* __restrict__ Vt)
{
    __shared__ f16 tile[64][72];
    const int t  = threadIdx.x;
    const int n0 = blockIdx.x * 64;
    const int b  = blockIdx.y;
    for (int i = t; i < 4096; i += 256) {
        int r = i >> 6, c = i & 63;
        tile[r][c] = Vh[(size_t)b * (Nn * Dd) + (size_t)(n0 + r) * 64 + c];
    }
    __syncthreads();
    for (int i = t; i < 4096; i += 256) {
        int w = i >> 6, n = i & 63;
        Vt[(size_t)b * (Dd * Nn) + (size_t)w * Nn + n0 + n] = tile[n][w];
    }
}

// ---------------------------------------------------------------------------
// Kernel 3: flash attention, split-K, double-buffered LDS, 1 barrier/tile.
// grid (32 q-blocks of 128 rows, S splits, 4 batches) x 256 threads (4 waves,
// 32 q-rows each). S^T = mfma(A=Kh, B=Q^T): lane holds
// S[key=fm*16+g*4+r][qrow = c of frag qf]. Scores are in log2 units.
__global__ __launch_bounds__(256, 3) void attn(
    const f16* __restrict__ Qhg, const f16* __restrict__ Qlg,
    const f16* __restrict__ Khg, const f16* __restrict__ Vtg,
    float* __restrict__ out, f16* __restrict__ Opart, float2* __restrict__ ml)
{
    __shared__ __align__(16) f16 KT[2][4096];  // [key 64][d 64] swizzled, dbuf
    __shared__ __align__(16) f16 VT[2][4096];  // [d 64][key 64] swizzled, dbuf
    __shared__ __align__(16) f16 Pt[8192];     // [128 qrows][64 keys] swizzled

    const int t    = threadIdx.x;
    const int lane = t & 63, wvi = t >> 6;
    const int g = lane >> 4, c = lane & 15;
    const int b  = blockIdx.z;
    const int sp = blockIdx.y;
    const int S  = gridDim.y;
    const int n0 = blockIdx.x * 128;
    const int keysPerSplit = Nn / S;
    const int nTiles = keysPerSplit / 64;
    const int kbase = sp * keysPerSplit;

    const int srow = t >> 3, scol = (t & 7) * 8;   // staging rows 0..31 (+32)
    const f16* Kb = Khg + (size_t)b * (Nn * Dd);
    const f16* Vb = Vtg + (size_t)b * (Dd * Nn);

    // Hoist Q B-fragments (hi/lo) for both 16-row sub-frags.
    f16x8 qbh[2][2], qbl[2][2];
    #pragma unroll
    for (int qf = 0; qf < 2; ++qf) {
        const int qrow = n0 + wvi * 32 + qf * 16 + c;
        const f16* qhp = Qhg + ((size_t)b * Nn + qrow) * 64;
        const f16* qlp = Qlg + ((size_t)b * Nn + qrow) * 64;
        #pragma unroll
        for (int ks = 0; ks < 2; ++ks) {
            qbh[qf][ks] = *(const f16x8*)(qhp + ks * 32 + g * 8);
            qbl[qf][ks] = *(const f16x8*)(qlp + ks * 32 + g * 8);
        }
    }

    float m_run[2] = {-1e30f, -1e30f}, l_run[2] = {0.f, 0.f};
    f32x4 of[2][4];
    #pragma unroll
    for (int qf = 0; qf < 2; ++qf)
        #pragma unroll
        for (int nf = 0; nf < 4; ++nf)
            #pragma unroll
            for (int r = 0; r < 4; ++r) of[qf][nf][r] = 0.f;

    // Prologue: stage tile 0 into buffer 0.
    {
        const int k0 = kbase;
        f16x8 a0 = *(const f16x8*)(Kb + (size_t)(k0 + srow) * 64 + scol);
        f16x8 a1 = *(const f16x8*)(Kb + (size_t)(k0 + srow + 32) * 64 + scol);
        f16x8 b0 = *(const f16x8*)(Vb + (size_t)srow * Nn + k0 + scol);
        f16x8 b1 = *(const f16x8*)(Vb + (size_t)(srow + 32) * Nn + k0 + scol);
        *(f16x8*)(KT[0] + swz(srow, scol))      = a0;
        *(f16x8*)(KT[0] + swz(srow + 32, scol)) = a1;
        *(f16x8*)(VT[0] + swz(srow, scol))      = b0;
        *(f16x8*)(VT[0] + swz(srow + 32, scol)) = b1;
    }
    __syncthreads();
    int cur = 0;

    for (int kt = 0; kt < nTiles; ++kt) {
        // Issue next tile's global loads; they land under this tile's compute.
        f16x8 rK0, rK1, rV0, rV1;
        const bool more = (kt + 1 < nTiles);
        if (more) {
            const int k0 = kbase + (kt + 1) * 64;
            rK0 = *(const f16x8*)(Kb + (size_t)(k0 + srow) * 64 + scol);
            rK1 = *(const f16x8*)(Kb + (size_t)(k0 + srow + 32) * 64 + scol);
            rV0 = *(const f16x8*)(Vb + (size_t)srow * Nn + k0 + scol);
            rV1 = *(const f16x8*)(Vb + (size_t)(srow + 32) * Nn + k0 + scol);
        }

        // ---- QK^T from KT[cur], 2-pass hi/lo (scores in log2 units) ----
        const f16* KTc = KT[cur];
        const f16* VTc = VT[cur];
        f32x4 accS[2][4];
        #pragma unroll
        for (int qf = 0; qf < 2; ++qf)
            #pragma unroll
            for (int fm = 0; fm < 4; ++fm)
                #pragma unroll
                for (int r = 0; r < 4; ++r) accS[qf][fm][r] = 0.f;
        #pragma unroll
        for (int fm = 0; fm < 4; ++fm) {
            const int key = fm * 16 + c;
            #pragma unroll
            for (int ks = 0; ks < 2; ++ks) {
                f16x8 kh = *(const f16x8*)(KTc + swz(key, ks * 32 + g * 8));
                #pragma unroll
                for (int qf = 0; qf < 2; ++qf) {
                    accS[qf][fm] = __builtin_amdgcn_mfma_f32_16x16x32_f16(kh, qbl[qf][ks], accS[qf][fm], 0, 0, 0);
                    accS[qf][fm] = __builtin_amdgcn_mfma_f32_16x16x32_f16(kh, qbh[qf][ks], accS[qf][fm], 0, 0, 0);
                }
            }
        }

        // ---- online softmax per q-frag; defer-max THR=8 (log2 units) ----
        #pragma unroll
        for (int qf = 0; qf < 2; ++qf) {
            // tree max of 16 values
            float m0 = fmaxf(fmaxf(accS[qf][0][0], accS[qf][0][1]),
                             fmaxf(accS[qf][0][2], accS[qf][0][3]));
            float m1 = fmaxf(fmaxf(accS[qf][1][0], accS[qf][1][1]),
                             fmaxf(accS[qf][1][2], accS[qf][1][3]));
            float m2 = fmaxf(fmaxf(accS[qf][2][0], accS[qf][2][1]),
                             fmaxf(accS[qf][2][2], accS[qf][2][3]));
            float m3 = fmaxf(fmaxf(accS[qf][3][0], accS[qf][3][1]),
                             fmaxf(accS[qf][3][2], accS[qf][3][3]));
            float tmax = fmaxf(fmaxf(m0, m1), fmaxf(m2, m3));
            tmax = fmaxf(tmax, __shfl_xor(tmax, 16));
            tmax = fmaxf(tmax, __shfl_xor(tmax, 32));
            if (!__all(tmax <= m_run[qf] + 8.f)) {
                const float mnew = fmaxf(m_run[qf], tmax);
                const float corr = exp2f(m_run[qf] - mnew);
                l_run[qf] *= corr;
                #pragma unroll
                for (int r = 0; r < 4; ++r) {
                    float cr = __shfl(corr, g * 4 + r);
                    #pragma unroll
                    for (int nf = 0; nf < 4; ++nf) of[qf][nf][r] *= cr;
                }
                m_run[qf] = mnew;
            }
            float s01 = 0.f, s23 = 0.f;
            #pragma unroll
            for (int fm = 0; fm < 4; ++fm)
                #pragma unroll
                for (int r = 0; r < 4; ++r) {
                    float pp = exp2f(accS[qf][fm][r] - m_run[qf]);  // <= 2^8
                    accS[qf][fm][r] = pp;
                    if (fm < 2) s01 += pp; else s23 += pp;
                }
            float tsum = s01 + s23;
            tsum += __shfl_xor(tsum, 16);
            tsum += __shfl_xor(tsum, 32);
            l_run[qf] += tsum;

            // stash P to LDS (wave-private rows, no barrier needed)
            const int prow = wvi * 32 + qf * 16 + c;
            #pragma unroll
            for (int fm = 0; fm < 4; ++fm) {
                f16x4 pk;
                #pragma unroll
                for (int r = 0; r < 4; ++r) pk[r] = (f16)accS[qf][fm][r];
                *(f16x4*)(Pt + swz(prow, fm * 16 + g * 4)) = pk;
            }
        }

        // ---- PV from VT[cur]: one V-read feeds both q-frags ----
        #pragma unroll
        for (int ks = 0; ks < 2; ++ks) {
            f16x8 pa0 = *(const f16x8*)(Pt + swz(wvi * 32 + c,      ks * 32 + g * 8));
            f16x8 pa1 = *(const f16x8*)(Pt + swz(wvi * 32 + 16 + c, ks * 32 + g * 8));
            #pragma unroll
            for (int nf = 0; nf < 4; ++nf) {
                f16x8 vb = *(const f16x8*)(VTc + swz(nf * 16 + c, ks * 32 + g * 8));
                of[0][nf] = __builtin_amdgcn_mfma_f32_16x16x32_f16(pa0, vb, of[0][nf], 0, 0, 0);
                of[1][nf] = __builtin_amdgcn_mfma_f32_16x16x32_f16(pa1, vb, of[1][nf], 0, 0, 0);
            }
        }

        // ---- stage next tile into the other buffer; single barrier ----
        if (more) {
            *(f16x8*)(KT[cur ^ 1] + swz(srow, scol))      = rK0;
            *(f16x8*)(KT[cur ^ 1] + swz(srow + 32, scol)) = rK1;
            *(f16x8*)(VT[cur ^ 1] + swz(srow, scol))      = rV0;
            *(f16x8*)(VT[cur ^ 1] + swz(srow + 32, scol)) = rV1;
            __syncthreads();
            cur ^= 1;
        }
    }

    if (S == 1) {
        #pragma unroll
        for (int qf = 0; qf < 2; ++qf) {
            const float linv = 1.0f / l_run[qf];
            #pragma unroll
            for (int r = 0; r < 4; ++r) {
                float li = __shfl(linv, g * 4 + r);
                int n = n0 + wvi * 32 + qf * 16 + g * 4 + r;
                #pragma unroll
                for (int nf = 0; nf < 4; ++nf)
                    out[((size_t)b * Nn + n) * 64 + nf * 16 + c] = of[qf][nf][r] * li;
            }
        }
    } else {
        // Normalized partials (O/l) in f16 + (m,l) per row; safe under defer-max.
        #pragma unroll
        for (int qf = 0; qf < 2; ++qf) {
            const float linv = 1.0f / l_run[qf];
            #pragma unroll
            for (int r = 0; r < 4; ++r) {
                float li = __shfl(linv, g * 4 + r);
                int n = n0 + wvi * 32 + qf * 16 + g * 4 + r;
                size_t robase = (((size_t)sp * Bn + b) * Nn + n) * 64;
                #pragma unroll
                for (int nf = 0; nf < 4; ++nf)
                    Opart[robase + nf * 16 + c] = (f16)(of[qf][nf][r] * li);
            }
            if (lane < 16) {
                int n = n0 + wvi * 32 + qf * 16 + c;
                ml[((size_t)sp * Bn + b) * Nn + n] = make_float2(m_run[qf], l_run[qf]);
            }
        }
    }
}

// ---------------------------------------------------------------------------
// Kernel 4: combine normalized split partials. 8 outputs per thread.
// weight_s = exp2(m_s - M) * l_s; out = sum w_s O_s / sum w_s.
__global__ __launch_bounds__(256) void combine(
    const f16* __restrict__ Opart, const float2* __restrict__ ml,
    float* __restrict__ out, int S)
{
    const int idx8 = blockIdx.x * 256 + threadIdx.x;  // b*(N*8) + n*8 + w8
    const int w8 = idx8 & 7;
    const int n  = (idx8 >> 3) & (Nn - 1);
    const int b  = idx8 >> 15;
    float M = -1e30f;
    for (int s = 0; s < S; ++s)
        M = fmaxf(M, ml[((size_t)s * Bn + b) * Nn + n].x);
    float num[8];
    #pragma unroll
    for (int j = 0; j < 8; ++j) num[j] = 0.f;
    float den = 0.f;
    for (int s = 0; s < S; ++s) {
        float2 m2 = ml[((size_t)s * Bn + b) * Nn + n];
        float a = exp2f(m2.x - M) * m2.y;
        f16x8 o8 = *(const f16x8*)(Opart + ((((size_t)s * Bn + b) * Nn + n) << 6) + w8 * 8);
        #pragma unroll
        for (int j = 0; j < 8; ++j) num[j] += a * (float)o8[j];
        den += a;
    }
    const float di = 1.0f / den;
    float* op = out + (((size_t)b * Nn + n) << 6) + w8 * 8;
    float4 lo = make_float4(num[0] * di, num[1] * di, num[2] * di, num[3] * di);
    float4 hi = make_float4(num[4] * di, num[5] * di, num[6] * di, num[7] * di);
    *(float4*)op = lo;
    *(float4*)(op + 4) = hi;
}

// ---------------------------------------------------------------------------
extern "C" void kernel_launch(void* const* d_in, const int* in_sizes, int n_in,
                              void* d_out, int out_size, void* d_ws, size_t ws_size,
                              hipStream_t stream)
{
    const float* v1 = (const float*)d_in[0];
    const float* v2 = (const float*)d_in[1];
    const float* wq = (const float*)d_in[2];
    const float* bq = (const float*)d_in[3];
    const float* wk = (const float*)d_in[4];
    const float* bk = (const float*)d_in[5];
    const float* wv = (const float*)d_in[6];
    const float* bv = (const float*)d_in[7];
    float* out = (float*)d_out;

    char* ws = (char*)d_ws;
    const size_t T = (size_t)TS * sizeof(f16);  // 2 MB per f16 tensor
    f16* Qh = (f16*)(ws + 0 * T);
    f16* Ql = (f16*)(ws + 1 * T);
    f16* Kh = (f16*)(ws + 2 * T);
    f16* Vh = (f16*)(ws + 3 * T);
    f16* Vt = (f16*)(ws + 4 * T);
    const size_t base = 5 * T;                       // 10 MB
    const size_t opartBytes = (size_t)TS * 2;        // 2 MB per split (f16)
    const size_t mlBytes    = (size_t)Bn * Nn * 8;   // 128 KB per split

    int S = 1;
    if      (ws_size >= base + 16 * (opartBytes + mlBytes)) S = 16;
    else if (ws_size >= base +  8 * (opartBytes + mlBytes)) S = 8;
    else if (ws_size >= base +  4 * (opartBytes + mlBytes)) S = 4;
    else if (ws_size >= base +  2 * (opartBytes + mlBytes)) S = 2;

    f16*    Opart = (f16*)(ws + base);
    float2* mlp   = (float2*)(ws + base + (size_t)S * opartBytes);

    qkv_conv<<<dim3(64, 4, 6), 256, 0, stream>>>(v1, v2, wq, bq, wk, bk, wv, bv,
                                                 Qh, Ql, Kh, Vh);
    vtrans<<<dim3(64, 4), 256, 0, stream>>>(Vh, Vt);
    attn<<<dim3(32, S, 4), 256, 0, stream>>>(Qh, Ql, Kh, Vt, out, Opart, mlp);
    if (S > 1) {
        combine<<<(Bn * Nn * Dd / 8) / 256, 256, 0, stream>>>(Opart, mlp, out, S);
    }
}

// Round 7
// 71.344 us; speedup vs baseline: 1.6664x; 1.1549x over previous
//
#include <hip/hip_runtime.h>

// B=4, C=64, H=64, W=64. Tokens N = C*H = 4096, feature dim D = W = 64.
// q = conv1x1(v1,wq,bq); k,v = conv1x1(v2,...); scores = q@k^T (no scale);
// softmax; out = attn@v. Output fp32, flat (B,C,H,W) == (B,N,D).
//
// R7: (1) single-pass f16 Q (drop Ql; R3->R4 showed f16 K rounding didn't move
//     absmax), (2) global_load_lds staging w/ pre-swizzled global source (no
//     VGPR roundtrip, no ds_write, 1 barrier/tile dbuf), (3) S=8 splits +
//     per-lane deferred l-reduction. Scores in log2 units (exp2 softmax).

#define Bn 4
#define Cc 64
#define HW 4096
#define Nn 4096
#define Dd 64
#define TS (Bn * Nn * Dd)   // elems per (B,N,D) tensor = 1048576
#define LOG2E 1.44269504088896340736f

typedef _Float16 f16;
typedef _Float16 f16x8 __attribute__((ext_vector_type(8)));
typedef _Float16 f16x4 __attribute__((ext_vector_type(4)));
typedef float f32x4 __attribute__((ext_vector_type(4)));

__device__ __forceinline__ int swz(int row, int col) {
    return row * 64 + (col ^ ((row & 7) << 3));
}

// Async global->LDS DMA, 16B per lane. LDS dest = uniform base + lane*16.
__device__ __forceinline__ void gl_lds16(const f16* g, f16* l) {
    __builtin_amdgcn_global_load_lds(
        (const __attribute__((address_space(1))) unsigned int*)g,
        (__attribute__((address_space(3))) unsigned int*)l, 16, 0, 0);
}

// ---------------------------------------------------------------------------
// Kernel 1: 1x1 conv. blockIdx.z 0..5: tensor = z>>1, channel-half = z&1.
// Q is single f16, pre-scaled by log2(e). SGPR (wave-uniform) weight reads.
__global__ __launch_bounds__(256) void qkv_conv(
    const float* __restrict__ v1, const float* __restrict__ v2,
    const float* __restrict__ wq, const float* __restrict__ bq,
    const float* __restrict__ wk, const float* __restrict__ bk,
    const float* __restrict__ wv, const float* __restrict__ bv,
    f16* __restrict__ Qh, f16* __restrict__ Kh, f16* __restrict__ Vh)
{
    const int t    = threadIdx.x;
    const int lane = t & 63;
    const int og   = __builtin_amdgcn_readfirstlane(t >> 6);  // 0..3 uniform
    const int b    = blockIdx.y;
    const int p    = blockIdx.x * 64 + lane;
    const int z    = blockIdx.z;        // 0..5
    const int zt   = z >> 1;            // 0=Q, 1=K, 2=V
    const int ch0  = (z & 1) * 32 + og * 8;

    const float* w    = (zt == 0) ? wq : (zt == 1) ? wk : wv;
    const float* bias = (zt == 0) ? bq : (zt == 1) ? bk : bv;
    const float* x    = ((zt == 0) ? v1 : v2) + (size_t)b * (Cc * HW) + p;

    float acc[8];
    #pragma unroll
    for (int j = 0; j < 8; ++j) acc[j] = bias[ch0 + j];
    #pragma unroll 16
    for (int c = 0; c < 64; ++c) {
        float xc = x[c * HW];
        #pragma unroll
        for (int j = 0; j < 8; ++j)
            acc[j] = fmaf(w[(ch0 + j) * 64 + c], xc, acc[j]);
    }

    f16* dst = (zt == 0) ? Qh : (zt == 1) ? Kh : Vh;
    const float scale = (zt == 0) ? LOG2E : 1.0f;
    #pragma unroll
    for (int j = 0; j < 8; ++j) {
        size_t idx = (size_t)b * (Nn * Dd) + (size_t)(ch0 + j) * 4096 + p;
        dst[idx] = (f16)(acc[j] * scale);
    }
}

// ---------------------------------------------------------------------------
// Kernel 2: transpose V (B,N,D) -> Vt (B,D,N).
__global__ __launch_bounds__(256) void vtrans(const f16* __restrict__ Vh,
                                              f16* __restrict__ Vt)
{
    __shared__ f16 tile[64][72];
    const int t  = threadIdx.x;
    const int n0 = blockIdx.x * 64;
    const int b  = blockIdx.y;
    for (int i = t; i < 4096; i += 256) {
        int r = i >> 6, c = i & 63;
        tile[r][c] = Vh[(size_t)b * (Nn * Dd) + (size_t)(n0 + r) * 64 + c];
    }
    __syncthreads();
    for (int i = t; i < 4096; i += 256) {
        int w = i >> 6, n = i & 63;
        Vt[(size_t)b * (Dd * Nn) + (size_t)w * Nn + n0 + n] = tile[n][w];
    }
}

// ---------------------------------------------------------------------------
// Kernel 3: flash attention, split-K, gload_lds-staged dbuf, 1 barrier/tile.
// grid (32 q-blocks of 128 rows, S splits, 4 batches) x 256 threads (4 waves,
// 32 q-rows each). S^T = mfma(A=K, B=Q^T): lane (g=lane>>4, c=lane&15) holds
// S[key=fm*16+g*4+r][qrow=c of frag qf]. Scores in log2 units.
__global__ __launch_bounds__(256, 3) void attn(
    const f16* __restrict__ Qhg, const f16* __restrict__ Khg,
    const f16* __restrict__ Vtg,
    float* __restrict__ out, f16* __restrict__ Opart, float2* __restrict__ ml)
{
    __shared__ __align__(16) f16 KT[2][4096];  // [key 64][d 64] swizzled, dbuf
    __shared__ __align__(16) f16 VT[2][4096];  // [d 64][key 64] swizzled, dbuf
    __shared__ __align__(16) f16 Pt[8192];     // [128 qrows][64 keys] swizzled

    const int t    = threadIdx.x;
    const int lane = t & 63, wvi = t >> 6;
    const int g = lane >> 4, c = lane & 15;
    const int rl = lane >> 3, cg = lane & 7;   // staging: row-in-8, col granule
    const int b  = blockIdx.z;
    const int sp = blockIdx.y;
    const int S  = gridDim.y;
    const int n0 = blockIdx.x * 128;
    const int keysPerSplit = Nn / S;
    const int nTiles = keysPerSplit / 64;
    const int kbase = sp * keysPerSplit;

    const f16* Kb = Khg + (size_t)b * (Nn * Dd);
    const f16* Vb = Vtg + (size_t)b * (Dd * Nn);

    // Hoist Q B-fragments (single f16, pre-scaled by log2e).
    f16x8 qbh[2][2];
    #pragma unroll
    for (int qf = 0; qf < 2; ++qf) {
        const int qrow = n0 + wvi * 32 + qf * 16 + c;
        const f16* qhp = Qhg + ((size_t)b * Nn + qrow) * 64;
        #pragma unroll
        for (int ks = 0; ks < 2; ++ks)
            qbh[qf][ks] = *(const f16x8*)(qhp + ks * 32 + g * 8);
    }

    float m_run[2] = {-1e30f, -1e30f}, lpart[2] = {0.f, 0.f};
    f32x4 of[2][4];
    #pragma unroll
    for (int qf = 0; qf < 2; ++qf)
        #pragma unroll
        for (int nf = 0; nf < 4; ++nf)
            #pragma unroll
            for (int r = 0; r < 4; ++r) of[qf][nf][r] = 0.f;

    // Prologue: DMA tile 0 into buffer 0 (wave wvi stages rows wvi*16..+15).
    {
        const int k0 = kbase;
        #pragma unroll
        for (int i = 0; i < 2; ++i) {
            const int row = wvi * 16 + i * 8 + rl;
            const int gc  = (cg ^ (row & 7)) * 8;   // pre-swizzled global col
            gl_lds16(Kb + (size_t)(k0 + row) * 64 + gc,
                     &KT[0][(wvi * 16 + i * 8) * 64]);
            gl_lds16(Vb + (size_t)row * Nn + k0 + gc,
                     &VT[0][(wvi * 16 + i * 8) * 64]);
        }
    }
    __syncthreads();
    int cur = 0;

    for (int kt = 0; kt < nTiles; ++kt) {
        // Issue next tile's DMA into the free buffer (lands under compute).
        if (kt + 1 < nTiles) {
            const int k0n = kbase + (kt + 1) * 64;
            #pragma unroll
            for (int i = 0; i < 2; ++i) {
                const int row = wvi * 16 + i * 8 + rl;
                const int gc  = (cg ^ (row & 7)) * 8;
                gl_lds16(Kb + (size_t)(k0n + row) * 64 + gc,
                         &KT[cur ^ 1][(wvi * 16 + i * 8) * 64]);
                gl_lds16(Vb + (size_t)row * Nn + k0n + gc,
                         &VT[cur ^ 1][(wvi * 16 + i * 8) * 64]);
            }
        }

        const f16* KTc = KT[cur];
        const f16* VTc = VT[cur];

        // ---- QK^T (single pass; scores in log2 units) ----
        f32x4 accS[2][4];
        #pragma unroll
        for (int qf = 0; qf < 2; ++qf)
            #pragma unroll
            for (int fm = 0; fm < 4; ++fm)
                #pragma unroll
                for (int r = 0; r < 4; ++r) accS[qf][fm][r] = 0.f;
        #pragma unroll
        for (int fm = 0; fm < 4; ++fm) {
            const int key = fm * 16 + c;
            f16x8 kh0 = *(const f16x8*)(KTc + swz(key, g * 8));
            f16x8 kh1 = *(const f16x8*)(KTc + swz(key, 32 + g * 8));
            #pragma unroll
            for (int qf = 0; qf < 2; ++qf) {
                accS[qf][fm] = __builtin_amdgcn_mfma_f32_16x16x32_f16(kh0, qbh[qf][0], accS[qf][fm], 0, 0, 0);
                accS[qf][fm] = __builtin_amdgcn_mfma_f32_16x16x32_f16(kh1, qbh[qf][1], accS[qf][fm], 0, 0, 0);
            }
        }

        // ---- online softmax; defer-max THR=8 (log2); per-lane partial l ----
        #pragma unroll
        for (int qf = 0; qf < 2; ++qf) {
            float m0 = fmaxf(fmaxf(accS[qf][0][0], accS[qf][0][1]),
                             fmaxf(accS[qf][0][2], accS[qf][0][3]));
            float m1 = fmaxf(fmaxf(accS[qf][1][0], accS[qf][1][1]),
                             fmaxf(accS[qf][1][2], accS[qf][1][3]));
            float m2 = fmaxf(fmaxf(accS[qf][2][0], accS[qf][2][1]),
                             fmaxf(accS[qf][2][2], accS[qf][2][3]));
            float m3 = fmaxf(fmaxf(accS[qf][3][0], accS[qf][3][1]),
                             fmaxf(accS[qf][3][2], accS[qf][3][3]));
            float tmax = fmaxf(fmaxf(m0, m1), fmaxf(m2, m3));
            tmax = fmaxf(tmax, __shfl_xor(tmax, 16));
            tmax = fmaxf(tmax, __shfl_xor(tmax, 32));
            if (!__all(tmax <= m_run[qf] + 8.f)) {
                const float mnew = fmaxf(m_run[qf], tmax);
                const float corr = exp2f(m_run[qf] - mnew);
                lpart[qf] *= corr;
                #pragma unroll
                for (int r = 0; r < 4; ++r) {
                    float cr = __shfl(corr, g * 4 + r);
                    #pragma unroll
                    for (int nf = 0; nf < 4; ++nf) of[qf][nf][r] *= cr;
                }
                m_run[qf] = mnew;
            }
            float s01 = 0.f, s23 = 0.f;
            #pragma unroll
            for (int fm = 0; fm < 4; ++fm)
                #pragma unroll
                for (int r = 0; r < 4; ++r) {
                    float pp = exp2f(accS[qf][fm][r] - m_run[qf]);  // <= 2^8
                    accS[qf][fm][r] = pp;
                    if (fm < 2) s01 += pp; else s23 += pp;
                }
            lpart[qf] += s01 + s23;   // per-lane; cross-lane reduce at epilogue

            // stash P to LDS (wave-private rows, no barrier needed)
            const int prow = wvi * 32 + qf * 16 + c;
            #pragma unroll
            for (int fm = 0; fm < 4; ++fm) {
                f16x4 pk;
                #pragma unroll
                for (int r = 0; r < 4; ++r) pk[r] = (f16)accS[qf][fm][r];
                *(f16x4*)(Pt + swz(prow, fm * 16 + g * 4)) = pk;
            }
        }

        // ---- PV: one V-read feeds both q-frags ----
        #pragma unroll
        for (int ks = 0; ks < 2; ++ks) {
            f16x8 pa0 = *(const f16x8*)(Pt + swz(wvi * 32 + c,      ks * 32 + g * 8));
            f16x8 pa1 = *(const f16x8*)(Pt + swz(wvi * 32 + 16 + c, ks * 32 + g * 8));
            #pragma unroll
            for (int nf = 0; nf < 4; ++nf) {
                f16x8 vb = *(const f16x8*)(VTc + swz(nf * 16 + c, ks * 32 + g * 8));
                of[0][nf] = __builtin_amdgcn_mfma_f32_16x16x32_f16(pa0, vb, of[0][nf], 0, 0, 0);
                of[1][nf] = __builtin_amdgcn_mfma_f32_16x16x32_f16(pa1, vb, of[1][nf], 0, 0, 0);
            }
        }

        // Barrier: compiler drains vmcnt(0) (DMA done) + lgkmcnt before it.
        __syncthreads();
        cur ^= 1;
    }

    if (S == 1) {
        #pragma unroll
        for (int qf = 0; qf < 2; ++qf) {
            float lr = lpart[qf];
            lr += __shfl_xor(lr, 16);
            lr += __shfl_xor(lr, 32);
            const float linv = 1.0f / lr;
            #pragma unroll
            for (int r = 0; r < 4; ++r) {
                float li = __shfl(linv, g * 4 + r);
                int n = n0 + wvi * 32 + qf * 16 + g * 4 + r;
                #pragma unroll
                for (int nf = 0; nf < 4; ++nf)
                    out[((size_t)b * Nn + n) * 64 + nf * 16 + c] = of[qf][nf][r] * li;
            }
        }
    } else {
        // Normalized f16 partials (O/l) + (m,l) per row for combine.
        #pragma unroll
        for (int qf = 0; qf < 2; ++qf) {
            float lr = lpart[qf];
            lr += __shfl_xor(lr, 16);
            lr += __shfl_xor(lr, 32);
            const float linv = 1.0f / lr;
            #pragma unroll
            for (int r = 0; r < 4; ++r) {
                float li = __shfl(linv, g * 4 + r);
                int n = n0 + wvi * 32 + qf * 16 + g * 4 + r;
                size_t robase = (((size_t)sp * Bn + b) * Nn + n) * 64;
                #pragma unroll
                for (int nf = 0; nf < 4; ++nf)
                    Opart[robase + nf * 16 + c] = (f16)(of[qf][nf][r] * li);
            }
            if (lane < 16) {
                int n = n0 + wvi * 32 + qf * 16 + c;
                ml[((size_t)sp * Bn + b) * Nn + n] = make_float2(m_run[qf], lr);
            }
        }
    }
}

// ---------------------------------------------------------------------------
// Kernel 4: combine normalized split partials. 8 outputs per thread.
// weight_s = exp2(m_s - M) * l_s; out = sum w_s O_s / sum w_s.
__global__ __launch_bounds__(256) void combine(
    const f16* __restrict__ Opart, const float2* __restrict__ ml,
    float* __restrict__ out, int S)
{
    const int idx8 = blockIdx.x * 256 + threadIdx.x;  // b*(N*8) + n*8 + w8
    const int w8 = idx8 & 7;
    const int n  = (idx8 >> 3) & (Nn - 1);
    const int b  = idx8 >> 15;
    float M = -1e30f;
    for (int s = 0; s < S; ++s)
        M = fmaxf(M, ml[((size_t)s * Bn + b) * Nn + n].x);
    float num[8];
    #pragma unroll
    for (int j = 0; j < 8; ++j) num[j] = 0.f;
    float den = 0.f;
    for (int s = 0; s < S; ++s) {
        float2 m2 = ml[((size_t)s * Bn + b) * Nn + n];
        float a = exp2f(m2.x - M) * m2.y;
        f16x8 o8 = *(const f16x8*)(Opart + ((((size_t)s * Bn + b) * Nn + n) << 6) + w8 * 8);
        #pragma unroll
        for (int j = 0; j < 8; ++j) num[j] += a * (float)o8[j];
        den += a;
    }
    const float di = 1.0f / den;
    float* op = out + (((size_t)b * Nn + n) << 6) + w8 * 8;
    float4 lo = make_float4(num[0] * di, num[1] * di, num[2] * di, num[3] * di);
    float4 hi = make_float4(num[4] * di, num[5] * di, num[6] * di, num[7] * di);
    *(float4*)op = lo;
    *(float4*)(op + 4) = hi;
}

// ---------------------------------------------------------------------------
extern "C" void kernel_launch(void* const* d_in, const int* in_sizes, int n_in,
                              void* d_out, int out_size, void* d_ws, size_t ws_size,
                              hipStream_t stream)
{
    const float* v1 = (const float*)d_in[0];
    const float* v2 = (const float*)d_in[1];
    const float* wq = (const float*)d_in[2];
    const float* bq = (const float*)d_in[3];
    const float* wk = (const float*)d_in[4];
    const float* bk = (const float*)d_in[5];
    const float* wv = (const float*)d_in[6];
    const float* bv = (const float*)d_in[7];
    float* out = (float*)d_out;

    char* ws = (char*)d_ws;
    const size_t T = (size_t)TS * sizeof(f16);  // 2 MB per f16 tensor
    f16* Qh = (f16*)(ws + 0 * T);
    f16* Kh = (f16*)(ws + 1 * T);
    f16* Vh = (f16*)(ws + 2 * T);
    f16* Vt = (f16*)(ws + 3 * T);
    const size_t base = 4 * T;                       // 8 MB
    const size_t opartBytes = (size_t)TS * 2;        // 2 MB per split (f16)
    const size_t mlBytes    = (size_t)Bn * Nn * 8;   // 128 KB per split

    int S = 1;
    if      (ws_size >= base + 8 * (opartBytes + mlBytes)) S = 8;
    else if (ws_size >= base + 4 * (opartBytes + mlBytes)) S = 4;
    else if (ws_size >= base + 2 * (opartBytes + mlBytes)) S = 2;

    f16*    Opart = (f16*)(ws + base);
    float2* mlp   = (float2*)(ws + base + (size_t)S * opartBytes);

    qkv_conv<<<dim3(64, 4, 6), 256, 0, stream>>>(v1, v2, wq, bq, wk, bk, wv, bv,
                                                 Qh, Kh, Vh);
    vtrans<<<dim3(64, 4), 256, 0, stream>>>(Vh, Vt);
    attn<<<dim3(32, S, 4), 256, 0, stream>>>(Qh, Kh, Vt, out, Opart, mlp);
    if (S > 1) {
        combine<<<(Bn * Nn * Dd / 8) / 256, 256, 0, stream>>>(Opart, mlp, out, S);
    }
}

// Round 9
// 69.622 us; speedup vs baseline: 1.7076x; 1.0247x over previous
//
#include <hip/hip_runtime.h>

// B=4, C=64, H=64, W=64. Tokens N = C*H = 4096, feature dim D = W = 64.
// q = conv1x1(v1,wq,bq); k,v = conv1x1(v2,...); scores = q@k^T (no scale);
// softmax; out = attn@v. Output fp32, flat (B,C,H,W) == (B,N,D).
//
// R9 = R8 with the cvt_pkrtz type fix (__fp16x2 union member).
// R8: occupancy restructure. R7 at 23% occupancy (48KB LDS -> 3 blocks/CU,
// 2048-block grid w/ tails). Now: 8-wave blocks (512 thr, 256 q-rows), LDS
// 64KB -> 2 blocks/CU = 16 waves/CU, grid EXACTLY 512 = one co-resident
// round. Staging cost per block unchanged (split 8 ways not 4).

#define Bn 4
#define Cc 64
#define HW 4096
#define Nn 4096
#define Dd 64
#define TS (Bn * Nn * Dd)   // elems per (B,N,D) tensor = 1048576
#define LOG2E 1.44269504088896340736f

typedef _Float16 f16;
typedef _Float16 f16x8 __attribute__((ext_vector_type(8)));
typedef _Float16 f16x4 __attribute__((ext_vector_type(4)));
typedef __fp16 fp16x2 __attribute__((ext_vector_type(2)));
typedef float f32x4 __attribute__((ext_vector_type(4)));

__device__ __forceinline__ int swz(int row, int col) {
    return row * 64 + (col ^ ((row & 7) << 3));
}

// Async global->LDS DMA, 16B per lane. LDS dest = uniform base + lane*16.
__device__ __forceinline__ void gl_lds16(const f16* g, f16* l) {
    __builtin_amdgcn_global_load_lds(
        (const __attribute__((address_space(1))) unsigned int*)g,
        (__attribute__((address_space(3))) unsigned int*)l, 16, 0, 0);
}

// ---------------------------------------------------------------------------
// Kernel 1: 1x1 conv. blockIdx.z 0..5: tensor = z>>1, channel-half = z&1.
// Q is single f16, pre-scaled by log2(e). SGPR (wave-uniform) weight reads.
__global__ __launch_bounds__(256) void qkv_conv(
    const float* __restrict__ v1, const float* __restrict__ v2,
    const float* __restrict__ wq, const float* __restrict__ bq,
    const float* __restrict__ wk, const float* __restrict__ bk,
    const float* __restrict__ wv, const float* __restrict__ bv,
    f16* __restrict__ Qh, f16* __restrict__ Kh, f16* __restrict__ Vh)
{
    const int t    = threadIdx.x;
    const int lane = t & 63;
    const int og   = __builtin_amdgcn_readfirstlane(t >> 6);  // 0..3 uniform
    const int b    = blockIdx.y;
    const int p    = blockIdx.x * 64 + lane;
    const int z    = blockIdx.z;        // 0..5
    const int zt   = z >> 1;            // 0=Q, 1=K, 2=V
    const int ch0  = (z & 1) * 32 + og * 8;

    const float* w    = (zt == 0) ? wq : (zt == 1) ? wk : wv;
    const float* bias = (zt == 0) ? bq : (zt == 1) ? bk : bv;
    const float* x    = ((zt == 0) ? v1 : v2) + (size_t)b * (Cc * HW) + p;

    float acc[8];
    #pragma unroll
    for (int j = 0; j < 8; ++j) acc[j] = bias[ch0 + j];
    #pragma unroll 16
    for (int c = 0; c < 64; ++c) {
        float xc = x[c * HW];
        #pragma unroll
        for (int j = 0; j < 8; ++j)
            acc[j] = fmaf(w[(ch0 + j) * 64 + c], xc, acc[j]);
    }

    f16* dst = (zt == 0) ? Qh : (zt == 1) ? Kh : Vh;
    const float scale = (zt == 0) ? LOG2E : 1.0f;
    #pragma unroll
    for (int j = 0; j < 8; ++j) {
        size_t idx = (size_t)b * (Nn * Dd) + (size_t)(ch0 + j) * 4096 + p;
        dst[idx] = (f16)(acc[j] * scale);
    }
}

// ---------------------------------------------------------------------------
// Kernel 2: transpose V (B,N,D) -> Vt (B,D,N).
__global__ __launch_bounds__(256) void vtrans(const f16* __restrict__ Vh,
                                              f16* __restrict__ Vt)
{
    __shared__ f16 tile[64][72];
    const int t  = threadIdx.x;
    const int n0 = blockIdx.x * 64;
    const int b  = blockIdx.y;
    for (int i = t; i < 4096; i += 256) {
        int r = i >> 6, c = i & 63;
        tile[r][c] = Vh[(size_t)b * (Nn * Dd) + (size_t)(n0 + r) * 64 + c];
    }
    __syncthreads();
    for (int i = t; i < 4096; i += 256) {
        int w = i >> 6, n = i & 63;
        Vt[(size_t)b * (Dd * Nn) + (size_t)w * Nn + n0 + n] = tile[n][w];
    }
}

// ---------------------------------------------------------------------------
// Kernel 3: flash attention, split-K. 512 threads = 8 waves x 32 q-rows.
// grid (16 q-blocks of 256 rows, S splits, 4 batches) -> 512 blocks at S=8
// = exactly 2 resident blocks/CU (one round, no tail). gload_lds dbuf K/V,
// 1 barrier/tile. S^T = mfma(A=K, B=Q^T): lane (g=lane>>4, c=lane&15) holds
// S[key=fm*16+g*4+r][qrow=c of frag qf]. Scores in log2 units.
__global__ __launch_bounds__(512, 4) void attn(
    const f16* __restrict__ Qhg, const f16* __restrict__ Khg,
    const f16* __restrict__ Vtg,
    float* __restrict__ out, f16* __restrict__ Opart, float2* __restrict__ ml)
{
    __shared__ __align__(16) f16 KT[2][4096];   // [key 64][d 64] swz, dbuf
    __shared__ __align__(16) f16 VT[2][4096];   // [d 64][key 64] swz, dbuf
    __shared__ __align__(16) f16 Pt[16384];     // [256 qrows][64 keys] swz

    const int t    = threadIdx.x;
    const int lane = t & 63, wvi = t >> 6;      // 8 waves
    const int g = lane >> 4, c = lane & 15;
    const int b  = blockIdx.z;
    const int sp = blockIdx.y;
    const int S  = gridDim.y;
    const int n0 = blockIdx.x * 256;
    const int keysPerSplit = Nn / S;
    const int nTiles = keysPerSplit / 64;
    const int kbase = sp * keysPerSplit;

    // Staging: 512 threads cover all 64 rows x 64 cols in one shot.
    const int srow = t >> 3;                    // 0..63
    const int gc   = ((t & 7) ^ (srow & 7)) * 8;  // pre-swizzled global col
    f16* ldsKdst0 = &KT[0][(wvi * 8) * 64];     // wave-uniform dests
    f16* ldsKdst1 = &KT[1][(wvi * 8) * 64];
    f16* ldsVdst0 = &VT[0][(wvi * 8) * 64];
    f16* ldsVdst1 = &VT[1][(wvi * 8) * 64];

    const f16* Kb = Khg + (size_t)b * (Nn * Dd);
    const f16* Vb = Vtg + (size_t)b * (Dd * Nn);

    // Hoist Q B-fragments (single f16, pre-scaled by log2e).
    f16x8 qbh[2][2];
    #pragma unroll
    for (int qf = 0; qf < 2; ++qf) {
        const int qrow = n0 + wvi * 32 + qf * 16 + c;
        const f16* qhp = Qhg + ((size_t)b * Nn + qrow) * 64;
        #pragma unroll
        for (int ks = 0; ks < 2; ++ks)
            qbh[qf][ks] = *(const f16x8*)(qhp + ks * 32 + g * 8);
    }

    float m_run[2] = {-1e30f, -1e30f}, lpart[2] = {0.f, 0.f};
    f32x4 of[2][4];
    #pragma unroll
    for (int qf = 0; qf < 2; ++qf)
        #pragma unroll
        for (int nf = 0; nf < 4; ++nf)
            #pragma unroll
            for (int r = 0; r < 4; ++r) of[qf][nf][r] = 0.f;

    // Prologue: DMA tile 0 into buffer 0.
    gl_lds16(Kb + (size_t)(kbase + srow) * 64 + gc, ldsKdst0);
    gl_lds16(Vb + (size_t)srow * Nn + kbase + gc, ldsVdst0);
    __syncthreads();
    int cur = 0;

    for (int kt = 0; kt < nTiles; ++kt) {
        // Issue next tile's DMA into the free buffer (lands under compute).
        if (kt + 1 < nTiles) {
            const int k0n = kbase + (kt + 1) * 64;
            f16* kd = cur ? ldsKdst0 : ldsKdst1;
            f16* vd = cur ? ldsVdst0 : ldsVdst1;
            gl_lds16(Kb + (size_t)(k0n + srow) * 64 + gc, kd);
            gl_lds16(Vb + (size_t)srow * Nn + k0n + gc, vd);
        }

        const f16* KTc = KT[cur];
        const f16* VTc = VT[cur];

        // ---- QK^T (single pass; scores in log2 units) ----
        f32x4 accS[2][4];
        #pragma unroll
        for (int qf = 0; qf < 2; ++qf)
            #pragma unroll
            for (int fm = 0; fm < 4; ++fm)
                #pragma unroll
                for (int r = 0; r < 4; ++r) accS[qf][fm][r] = 0.f;
        #pragma unroll
        for (int fm = 0; fm < 4; ++fm) {
            const int key = fm * 16 + c;
            f16x8 kh0 = *(const f16x8*)(KTc + swz(key, g * 8));
            f16x8 kh1 = *(const f16x8*)(KTc + swz(key, 32 + g * 8));
            #pragma unroll
            for (int qf = 0; qf < 2; ++qf) {
                accS[qf][fm] = __builtin_amdgcn_mfma_f32_16x16x32_f16(kh0, qbh[qf][0], accS[qf][fm], 0, 0, 0);
                accS[qf][fm] = __builtin_amdgcn_mfma_f32_16x16x32_f16(kh1, qbh[qf][1], accS[qf][fm], 0, 0, 0);
            }
        }

        // ---- online softmax; defer-max THR=8 (log2); per-lane partial l ----
        #pragma unroll
        for (int qf = 0; qf < 2; ++qf) {
            float m0 = fmaxf(fmaxf(accS[qf][0][0], accS[qf][0][1]),
                             fmaxf(accS[qf][0][2], accS[qf][0][3]));
            float m1 = fmaxf(fmaxf(accS[qf][1][0], accS[qf][1][1]),
                             fmaxf(accS[qf][1][2], accS[qf][1][3]));
            float m2 = fmaxf(fmaxf(accS[qf][2][0], accS[qf][2][1]),
                             fmaxf(accS[qf][2][2], accS[qf][2][3]));
            float m3 = fmaxf(fmaxf(accS[qf][3][0], accS[qf][3][1]),
                             fmaxf(accS[qf][3][2], accS[qf][3][3]));
            float tmax = fmaxf(fmaxf(m0, m1), fmaxf(m2, m3));
            tmax = fmaxf(tmax, __shfl_xor(tmax, 16));
            tmax = fmaxf(tmax, __shfl_xor(tmax, 32));
            if (!__all(tmax <= m_run[qf] + 8.f)) {
                const float mnew = fmaxf(m_run[qf], tmax);
                const float corr = exp2f(m_run[qf] - mnew);
                lpart[qf] *= corr;
                #pragma unroll
                for (int r = 0; r < 4; ++r) {
                    float cr = __shfl(corr, g * 4 + r);
                    #pragma unroll
                    for (int nf = 0; nf < 4; ++nf) of[qf][nf][r] *= cr;
                }
                m_run[qf] = mnew;
            }
            float s01 = 0.f, s23 = 0.f;
            #pragma unroll
            for (int fm = 0; fm < 4; ++fm)
                #pragma unroll
                for (int r = 0; r < 4; ++r) {
                    float pp = exp2f(accS[qf][fm][r] - m_run[qf]);  // <= 2^8
                    accS[qf][fm][r] = pp;
                    if (fm < 2) s01 += pp; else s23 += pp;
                }
            lpart[qf] += s01 + s23;   // per-lane; reduce at epilogue

            // stash P to LDS (wave-private rows; packed converts)
            const int prow = wvi * 32 + qf * 16 + c;
            #pragma unroll
            for (int fm = 0; fm < 4; ++fm) {
                union { f16x4 v4; fp16x2 h2[2]; } u;
                u.h2[0] = __builtin_amdgcn_cvt_pkrtz(accS[qf][fm][0], accS[qf][fm][1]);
                u.h2[1] = __builtin_amdgcn_cvt_pkrtz(accS[qf][fm][2], accS[qf][fm][3]);
                *(f16x4*)(Pt + swz(prow, fm * 16 + g * 4)) = u.v4;
            }
        }

        // ---- PV: one V-read feeds both q-frags ----
        #pragma unroll
        for (int ks = 0; ks < 2; ++ks) {
            f16x8 pa0 = *(const f16x8*)(Pt + swz(wvi * 32 + c,      ks * 32 + g * 8));
            f16x8 pa1 = *(const f16x8*)(Pt + swz(wvi * 32 + 16 + c, ks * 32 + g * 8));
            #pragma unroll
            for (int nf = 0; nf < 4; ++nf) {
                f16x8 vb = *(const f16x8*)(VTc + swz(nf * 16 + c, ks * 32 + g * 8));
                of[0][nf] = __builtin_amdgcn_mfma_f32_16x16x32_f16(pa0, vb, of[0][nf], 0, 0, 0);
                of[1][nf] = __builtin_amdgcn_mfma_f32_16x16x32_f16(pa1, vb, of[1][nf], 0, 0, 0);
            }
        }

        // Barrier: compiler drains vmcnt (DMA done) + lgkmcnt before it.
        __syncthreads();
        cur ^= 1;
    }

    if (S == 1) {
        #pragma unroll
        for (int qf = 0; qf < 2; ++qf) {
            float lr = lpart[qf];
            lr += __shfl_xor(lr, 16);
            lr += __shfl_xor(lr, 32);
            const float linv = 1.0f / lr;
            #pragma unroll
            for (int r = 0; r < 4; ++r) {
                float li = __shfl(linv, g * 4 + r);
                int n = n0 + wvi * 32 + qf * 16 + g * 4 + r;
                #pragma unroll
                for (int nf = 0; nf < 4; ++nf)
                    out[((size_t)b * Nn + n) * 64 + nf * 16 + c] = of[qf][nf][r] * li;
            }
        }
    } else {
        // Normalized f16 partials (O/l) + (m,l) per row for combine.
        #pragma unroll
        for (int qf = 0; qf < 2; ++qf) {
            float lr = lpart[qf];
            lr += __shfl_xor(lr, 16);
            lr += __shfl_xor(lr, 32);
            const float linv = 1.0f / lr;
            #pragma unroll
            for (int r = 0; r < 4; ++r) {
                float li = __shfl(linv, g * 4 + r);
                int n = n0 + wvi * 32 + qf * 16 + g * 4 + r;
                size_t robase = (((size_t)sp * Bn + b) * Nn + n) * 64;
                #pragma unroll
                for (int nf = 0; nf < 4; ++nf)
                    Opart[robase + nf * 16 + c] = (f16)(of[qf][nf][r] * li);
            }
            if (lane < 16) {
                int n = n0 + wvi * 32 + qf * 16 + c;
                ml[((size_t)sp * Bn + b) * Nn + n] = make_float2(m_run[qf], lr);
            }
        }
    }
}

// ---------------------------------------------------------------------------
// Kernel 4: combine normalized split partials. 8 outputs per thread.
// weight_s = exp2(m_s - M) * l_s; out = sum w_s O_s / sum w_s.
__global__ __launch_bounds__(256) void combine(
    const f16* __restrict__ Opart, const float2* __restrict__ ml,
    float* __restrict__ out, int S)
{
    const int idx8 = blockIdx.x * 256 + threadIdx.x;  // b*(N*8) + n*8 + w8
    const int w8 = idx8 & 7;
    const int n  = (idx8 >> 3) & (Nn - 1);
    const int b  = idx8 >> 15;
    float M = -1e30f;
    for (int s = 0; s < S; ++s)
        M = fmaxf(M, ml[((size_t)s * Bn + b) * Nn + n].x);
    float num[8];
    #pragma unroll
    for (int j = 0; j < 8; ++j) num[j] = 0.f;
    float den = 0.f;
    for (int s = 0; s < S; ++s) {
        float2 m2 = ml[((size_t)s * Bn + b) * Nn + n];
        float a = exp2f(m2.x - M) * m2.y;
        f16x8 o8 = *(const f16x8*)(Opart + ((((size_t)s * Bn + b) * Nn + n) << 6) + w8 * 8);
        #pragma unroll
        for (int j = 0; j < 8; ++j) num[j] += a * (float)o8[j];
        den += a;
    }
    const float di = 1.0f / den;
    float* op = out + (((size_t)b * Nn + n) << 6) + w8 * 8;
    float4 lo = make_float4(num[0] * di, num[1] * di, num[2] * di, num[3] * di);
    float4 hi = make_float4(num[4] * di, num[5] * di, num[6] * di, num[7] * di);
    *(float4*)op = lo;
    *(float4*)(op + 4) = hi;
}

// ---------------------------------------------------------------------------
extern "C" void kernel_launch(void* const* d_in, const int* in_sizes, int n_in,
                              void* d_out, int out_size, void* d_ws, size_t ws_size,
                              hipStream_t stream)
{
    const float* v1 = (const float*)d_in[0];
    const float* v2 = (const float*)d_in[1];
    const float* wq = (const float*)d_in[2];
    const float* bq = (const float*)d_in[3];
    const float* wk = (const float*)d_in[4];
    const float* bk = (const float*)d_in[5];
    const float* wv = (const float*)d_in[6];
    const float* bv = (const float*)d_in[7];
    float* out = (float*)d_out;

    char* ws = (char*)d_ws;
    const size_t T = (size_t)TS * sizeof(f16);  // 2 MB per f16 tensor
    f16* Qh = (f16*)(ws + 0 * T);
    f16* Kh = (f16*)(ws + 1 * T);
    f16* Vh = (f16*)(ws + 2 * T);
    f16* Vt = (f16*)(ws + 3 * T);
    const size_t base = 4 * T;                       // 8 MB
    const size_t opartBytes = (size_t)TS * 2;        // 2 MB per split (f16)
    const size_t mlBytes    = (size_t)Bn * Nn * 8;   // 128 KB per split

    int S = 1;
    if      (ws_size >= base + 8 * (opartBytes + mlBytes)) S = 8;
    else if (ws_size >= base + 4 * (opartBytes + mlBytes)) S = 4;
    else if (ws_size >= base + 2 * (opartBytes + mlBytes)) S = 2;

    f16*    Opart = (f16*)(ws + base);
    float2* mlp   = (float2*)(ws + base + (size_t)S * opartBytes);

    qkv_conv<<<dim3(64, 4, 6), 256, 0, stream>>>(v1, v2, wq, bq, wk, bk, wv, bv,
                                                 Qh, Kh, Vh);
    vtrans<<<dim3(64, 4), 256, 0, stream>>>(Vh, Vt);
    attn<<<dim3(16, S, 4), 512, 0, stream>>>(Qh, Kh, Vt, out, Opart, mlp);
    if (S > 1) {
        combine<<<(Bn * Nn * Dd / 8) / 256, 256, 0, stream>>>(Opart, mlp, out, S);
    }
}